// Round 4
// baseline (3076.620 us; speedup 1.0000x reference)
//
#include <hip/hip_runtime.h>
#include <stdint.h>

// BinaryLinearLayer: out = sign(x) @ sign(w), x:[8192,4096] f32, w:[4096,4096] f32.
// Exact path via i8 MFMA (K-sums <= 4096, exact in i32).
// R4: occupancy attack. MfmaUtil pinned at 35-37% across 3 schedules at
// 1 block/CU (128KB LDS, 2 waves/SIMD): ~2500cy/K-tile of barrier/latency
// slack that 2 waves can't cover. BK 128->64: LDS 64KB -> 2 blocks/CU
// (4 waves/SIMD TLP). Double-buffer makes mid-phase barriers redundant ->
// 1 barrier + 1 vmcnt(0) per K-tile, stage-first, compiler free-schedules
// ds_read/MFMA interleave (it emits fine lgkmcnt; m97 evidence).
// Bank conflicts proven inert (R2/R3 bit-identical 1.258e7); XCD swizzle
// proven inert (L3-resident) - both kept/neutral.

#define DIN  4096
#define DOUT 4096
#define BM   256
#define BN   256
#define BK   64             // i8 k-elems per LDS K-tile = 64B rows
#define NT   (DIN / BK)     // 64 K-tiles

typedef __attribute__((ext_vector_type(4)))  int v4i;
typedef __attribute__((ext_vector_type(16))) int v16i;
typedef unsigned int u32;

__device__ __forceinline__ void cp16(void* lds, const void* g) {
    __builtin_amdgcn_global_load_lds((const __attribute__((address_space(1))) u32*)g,
                                     (__attribute__((address_space(3))) u32*)lds,
                                     16, 0, 0);
}

// ---- x [N,DIN] f32 -> xb [N,DIN] i8 (+1/-1): 64B read / 16B write per thread ----
__global__ __launch_bounds__(256) void pack_x_i8(const float* __restrict__ x,
                                                 signed char* __restrict__ xb) {
    size_t g = (size_t)blockIdx.x * 256 + threadIdx.x;   // 16-float group index
    const float4* xv = (const float4*)x + g * 4;
    v4i o;
    #pragma unroll
    for (int q = 0; q < 4; q++) {
        float4 v = xv[q];
        int c0 = v.x >= 0.f ? 1 : 0xFF;
        int c1 = v.y >= 0.f ? 1 : 0xFF;
        int c2 = v.z >= 0.f ? 1 : 0xFF;
        int c3 = v.w >= 0.f ? 1 : 0xFF;
        o[q] = c0 | (c1 << 8) | (c2 << 16) | (c3 << 24);
    }
    ((v4i*)xb)[g] = o;
}

// ---- w [DIN,DOUT] f32 -> wbT [DOUT,DIN] i8: wbT[n][k] = sign(w[k][n]) ----
__global__ __launch_bounds__(256) void pack_wT_i8(const float* __restrict__ w,
                                                  signed char* __restrict__ wbT) {
    __shared__ signed char tile[64][80];   // stride 80: 16B-aligned rows, breaks pow2
    const int k0 = blockIdx.y * 64, n0 = blockIdx.x * 64;
    const int t = threadIdx.x;
    const int j4 = (t & 15) * 4;    // n offset (float4)
    const int i0 = t >> 4;          // k row 0..15
    #pragma unroll
    for (int s = 0; s < 4; s++) {
        int i = i0 + s * 16;        // k offset
        float4 v = *(const float4*)&w[(size_t)(k0 + i) * DOUT + n0 + j4];
        tile[j4 + 0][i] = v.x >= 0.f ? 1 : -1;
        tile[j4 + 1][i] = v.y >= 0.f ? 1 : -1;
        tile[j4 + 2][i] = v.z >= 0.f ? 1 : -1;
        tile[j4 + 3][i] = v.w >= 0.f ? 1 : -1;
    }
    __syncthreads();
    const int n  = t >> 2;          // 0..63
    const int kk = (t & 3) * 16;    // byte offset within row
    v4i val = *(const v4i*)&tile[n][kk];
    *(v4i*)&wbT[(size_t)(n0 + n) * DIN + k0 + kk] = val;
}

// ---- 256^2 8-wave i8 MFMA GEMM (32x32x32), BK=64, 2 blocks/CU ----
// 512 thr = 8 waves (2M x 4N); per-wave C = 128x64 = 4x2 frags of 32x32.
// LDS tile: 256 rows x 64B = 16 blocks of 1KB; block(g=row>>5, ks=kcol>>5)
// at (g*2+ks)*1024; in-block (row&31)*32 + hi*16 (hi = kcol bit4).
// Frag read = contiguous 1024B/wave. Staging unit = 128 rows = 8KB: thread t
// -> LDS unit_base + t*16; global row = (t>>7&3)*32 + (t&63)>>1,
// col = (t>>6&1)*32 + (t&1)*16  (write image == read image, audited).
// Loop: [stage 4 units -> nxt] [16 ds_read cur] [16 MFMA, setprio] vmcnt(0)
// barrier.  Mid barriers removed: stage targets nxt, whose previous readers
// all passed the preceding tile-end barrier (lgkm-complete before barrier).
__global__ __launch_bounds__(512, 4) void bgemm_i8(const signed char* __restrict__ xb,
                                                   const signed char* __restrict__ wbT,
                                                   float* __restrict__ out) {
    __shared__ __align__(16) signed char As[2][BM * BK];   // 2 x 16 KB
    __shared__ __align__(16) signed char Bs[2][BN * BK];   // 2 x 16 KB  (64 KB)

    const int t = threadIdx.x;
    const int l = t & 63;
    const int w = t >> 6;          // 8 waves
    const int wr = w & 1;          // A half: rows wr*128..+127 (g = wr*4+i)
    const int wc = w >> 1;         // B band: rows wc*64..+63  (g = wc*2+j)
    const int lm = l & 31;         // frag row lane
    const int hi = l >> 5;         // k-half within 32B
    const int loff = (lm << 5) + (hi << 4);   // in-block lane offset

    const int fid = blockIdx.y * gridDim.x + blockIdx.x;
    const int swz = (fid & 7) * 64 + (fid >> 3);
    const int bm = (swz >> 4) * BM, bn = (swz & 15) * BN;

    const signed char* gA = xb  + (size_t)bm * DIN;
    const signed char* gB = wbT + (size_t)bn * DIN;

    // staging source permutation matching the blocked LDS layout
    const int    srow = ((t >> 7) & 3) * 32 + ((t & 63) >> 1);
    const int    scol = ((t >> 6) & 1) * 32 + (t & 1) * 16;
    const size_t soff = (size_t)srow * DIN + scol;
    const int    ldst = t * 16;

#define SU(lbuf, gmat, r0, kk) \
    cp16(&(lbuf)[(r0) * BK + ldst], (gmat) + (size_t)(r0) * DIN + (size_t)(kk) + soff)

    v16i acc[4][2];
    #pragma unroll
    for (int i = 0; i < 4; i++)
        #pragma unroll
        for (int j = 0; j < 2; j++)
            #pragma unroll
            for (int r = 0; r < 16; r++)
                acc[i][j][r] = 0;

    // prologue: K-tile 0 -> buf 0
    SU(Bs[0], gB, 0, 0); SU(Bs[0], gB, 128, 0);
    SU(As[0], gA, 0, 0); SU(As[0], gA, 128, 0);
    asm volatile("s_waitcnt vmcnt(0)" ::: "memory");
    __builtin_amdgcn_s_barrier();
    __builtin_amdgcn_sched_barrier(0);

    #pragma unroll 2
    for (int kt = 0; kt < NT - 1; ++kt) {
        const int cur = kt & 1, nxt = cur ^ 1;
        const int kk = (kt + 1) * BK;
        // stage first: max latency cover before the tile-end vmcnt(0)
        SU(Bs[nxt], gB, 0, kk); SU(Bs[nxt], gB, 128, kk);
        SU(As[nxt], gA, 0, kk); SU(As[nxt], gA, 128, kk);

        v4i a[4][2], b[2][2];
        #pragma unroll
        for (int i = 0; i < 4; ++i) {
            const signed char* ap = &As[cur][(wr * 4 + i) * 2048 + loff];
            a[i][0] = *(const v4i*)(ap);
            a[i][1] = *(const v4i*)(ap + 1024);
        }
        #pragma unroll
        for (int j = 0; j < 2; ++j) {
            const signed char* bp = &Bs[cur][(wc * 2 + j) * 2048 + loff];
            b[j][0] = *(const v4i*)(bp);
            b[j][1] = *(const v4i*)(bp + 1024);
        }

        __builtin_amdgcn_s_setprio(1);
        #pragma unroll
        for (int ks = 0; ks < 2; ++ks)
            #pragma unroll
            for (int i = 0; i < 4; ++i)
                #pragma unroll
                for (int j = 0; j < 2; ++j)
                    acc[i][j] = __builtin_amdgcn_mfma_i32_32x32x32_i8(
                        a[i][ks], b[j][ks], acc[i][j], 0, 0, 0);
        __builtin_amdgcn_s_setprio(0);

        asm volatile("s_waitcnt vmcnt(0)" ::: "memory");
        __builtin_amdgcn_sched_barrier(0);
        __builtin_amdgcn_s_barrier();
        __builtin_amdgcn_sched_barrier(0);
    }

    // peeled last K-tile (no prefetch)
    {
        const int cur = (NT - 1) & 1;
        v4i a[4][2], b[2][2];
        #pragma unroll
        for (int i = 0; i < 4; ++i) {
            const signed char* ap = &As[cur][(wr * 4 + i) * 2048 + loff];
            a[i][0] = *(const v4i*)(ap);
            a[i][1] = *(const v4i*)(ap + 1024);
        }
        #pragma unroll
        for (int j = 0; j < 2; ++j) {
            const signed char* bp = &Bs[cur][(wc * 2 + j) * 2048 + loff];
            b[j][0] = *(const v4i*)(bp);
            b[j][1] = *(const v4i*)(bp + 1024);
        }
        __builtin_amdgcn_s_setprio(1);
        #pragma unroll
        for (int ks = 0; ks < 2; ++ks)
            #pragma unroll
            for (int i = 0; i < 4; ++i)
                #pragma unroll
                for (int j = 0; j < 2; ++j)
                    acc[i][j] = __builtin_amdgcn_mfma_i32_32x32x32_i8(
                        a[i][ks], b[j][ks], acc[i][j], 0, 0, 0);
        __builtin_amdgcn_s_setprio(0);
    }
#undef SU

    // epilogue: C/D col=l&31, row=(r&3)+8*(r>>2)+4*hi (shape-determined)
    #pragma unroll
    for (int f = 0; f < 4; f++) {
        #pragma unroll
        for (int g = 0; g < 2; g++) {
            int col = bn + wc * 64 + g * 32 + lm;
            #pragma unroll
            for (int r = 0; r < 16; r++) {
                int row = bm + wr * 128 + f * 32 + (r & 3) + 8 * (r >> 2) + 4 * hi;
                out[(size_t)row * DOUT + col] = (float)acc[f][g][r];
            }
        }
    }
}

extern "C" void kernel_launch(void* const* d_in, const int* in_sizes, int n_in,
                              void* d_out, int out_size, void* d_ws, size_t ws_size,
                              hipStream_t stream) {
    const float* x = (const float*)d_in[0];
    const float* w = (const float*)d_in[1];
    float* out = (float*)d_out;
    const int N = in_sizes[0] / DIN;                       // 8192

    signed char* xb  = (signed char*)d_ws;                 // 32 MB
    signed char* wbT = (signed char*)d_ws + (size_t)N * DIN;  // 16 MB

    pack_x_i8<<<(N * DIN) / (16 * 256), 256, 0, stream>>>(x, xb);
    pack_wT_i8<<<dim3(DOUT / 64, DIN / 64), 256, 0, stream>>>(w, wbT);
    bgemm_i8<<<dim3(DOUT / BN, N / BM), 512, 0, stream>>>(xb, wbT, out);
}